// Round 1
// baseline (165.685 us; speedup 1.0000x reference)
//
#include <hip/hip_runtime.h>
#include <stdint.h>
#include <stddef.h>

// Problem constants (B=32, T=512, C=256, H=8, D=32)
#define NB 32
#define NT 512
#define NC 256
#define NH 8
#define ND 32
#define NQTOT (NB*NH*NT*ND)   // 4194304 elements per Q/K/V tensor

typedef __attribute__((ext_vector_type(8))) short short8;
typedef __attribute__((ext_vector_type(4))) float f32x4;

// f32 -> bf16 round-to-nearest-even (inputs are normal floats; no NaN handling needed)
__device__ __forceinline__ unsigned short f2bf(float f) {
    union { float f; unsigned u; } x; x.f = f;
    unsigned r = (x.u + 0x7FFFu + ((x.u >> 16) & 1u)) >> 16;
    return (unsigned short)r;
}

// ---------------- prep kernels ----------------
__global__ __launch_bounds__(256) void k_cvt_x(const float* __restrict__ x,
                                               unsigned short* __restrict__ xb, int n4) {
    int i = blockIdx.x * 256 + threadIdx.x;
    if (i < n4) {
        float4 v = reinterpret_cast<const float4*>(x)[i];
        ushort4 o;
        o.x = f2bf(v.x); o.y = f2bf(v.y); o.z = f2bf(v.z); o.w = f2bf(v.w);
        reinterpret_cast<ushort4*>(xb)[i] = o;
    }
}

// w: [K][N] f32  ->  wt: [N][K] bf16   (coalesced writes, strided reads; small, L2-resident)
__global__ __launch_bounds__(256) void k_cvt_wT(const float* __restrict__ w,
                                                unsigned short* __restrict__ wt, int K, int N) {
    int idx = blockIdx.x * 256 + threadIdx.x;
    if (idx < K * N) {
        int n = idx / K;
        int k = idx - n * K;
        wt[idx] = f2bf(w[(size_t)k * N + n]);
    }
}

// ---------------- bf16 MFMA GEMM: C = A[M,K] * Bt[N,K]^T + bias ----------------
// 128x128 tile, BK=32, 256 threads (4 waves, 2x2), each wave 64x64 (4x4 16x16 frags).
// EPI 0: scatter to Q/K/V [B,H,T,D] bf16.  EPI 1: f32 out [M,N] + bias.
template <int EPI>
__global__ __launch_bounds__(256) void k_gemm(const unsigned short* __restrict__ A,
                                              const unsigned short* __restrict__ Bt,
                                              const float* __restrict__ bias,
                                              unsigned short* __restrict__ qkv,
                                              float* __restrict__ outf,
                                              int M, int N, int K) {
    __shared__ unsigned short Al[128][40];   // +8 pad: frag reads ~2-way, rows 16B-aligned (80B)
    __shared__ unsigned short Bl[128][40];

    const int tid = threadIdx.x;
    const int lane = tid & 63;
    const int w = tid >> 6;
    const int wm = w >> 1, wn = w & 1;
    const int i16 = lane & 15, g = lane >> 4;

    const int nbm = M >> 7;
    const int bm = blockIdx.x % nbm;
    const int bn = blockIdx.x / nbm;
    const int m0 = bm << 7, n0 = bn << 7;

    f32x4 acc[4][4];
    const f32x4 z4 = {0.f, 0.f, 0.f, 0.f};
#pragma unroll
    for (int a = 0; a < 4; a++)
#pragma unroll
        for (int b = 0; b < 4; b++) acc[a][b] = z4;

    const int row0 = tid >> 2;   // 0..63
    const int cr = tid & 3;      // k-chunk within row (8 bf16 each)

    for (int k0 = 0; k0 < K; k0 += 32) {
        __syncthreads();   // previous compute done before overwrite
#pragma unroll
        for (int half = 0; half < 2; ++half) {
            int row = row0 + half * 64;
            *reinterpret_cast<short8*>(&Al[row][cr * 8]) =
                *reinterpret_cast<const short8*>(&A[(size_t)(m0 + row) * K + k0 + cr * 8]);
            *reinterpret_cast<short8*>(&Bl[row][cr * 8]) =
                *reinterpret_cast<const short8*>(&Bt[(size_t)(n0 + row) * K + k0 + cr * 8]);
        }
        __syncthreads();

        short8 af[4], bf[4];
#pragma unroll
        for (int mi = 0; mi < 4; mi++)
            af[mi] = *reinterpret_cast<const short8*>(&Al[wm * 64 + mi * 16 + i16][g * 8]);
#pragma unroll
        for (int ni = 0; ni < 4; ni++)
            bf[ni] = *reinterpret_cast<const short8*>(&Bl[wn * 64 + ni * 16 + i16][g * 8]);
#pragma unroll
        for (int mi = 0; mi < 4; mi++)
#pragma unroll
            for (int ni = 0; ni < 4; ni++)
                acc[mi][ni] = __builtin_amdgcn_mfma_f32_16x16x32_bf16(af[mi], bf[ni], acc[mi][ni], 0, 0, 0);
    }

    // epilogue: C/D layout col=lane&15, row=(lane>>4)*4+reg  [verified m89]
#pragma unroll
    for (int mi = 0; mi < 4; mi++) {
#pragma unroll
        for (int ni = 0; ni < 4; ni++) {
            const int col = n0 + wn * 64 + ni * 16 + i16;
            const float bv = bias[col];
#pragma unroll
            for (int r = 0; r < 4; r++) {
                const int rowg = m0 + wm * 64 + mi * 16 + g * 4 + r;
                const float v = acc[mi][ni][r] + bv;
                if (EPI == 0) {
                    // col in [0,768): which (Q/K/V), head, dim; row: batch, token
                    const int which = col >> 8;
                    const int cc = col & 255;
                    const int h = cc >> 5, d = cc & 31;
                    const int bb = rowg >> 9, t = rowg & 511;
                    qkv[(size_t)which * NQTOT +
                        ((((size_t)bb * NH + h) * NT + t) * ND) + d] = f2bf(v);
                } else {
                    outf[(size_t)rowg * N + col] = v;
                }
            }
        }
    }
}

// ---------------- causal flash attention ----------------
// One block = (b,h, 64 q-rows); 4 waves x 16 q-rows. K-tiles of 64 keys.
// QK^T and PV via 16x16x32 bf16 MFMA; online softmax with 16-lane shfl reductions.
__global__ __launch_bounds__(256) void k_attn(const unsigned short* __restrict__ qkv,
                                              unsigned short* __restrict__ Ob) {
    __shared__ unsigned short Kl[64][40];     // [key][d]  (padded)
    __shared__ unsigned short Vt[32][72];     // [d][key]  (transposed; 144B rows, 16B-aligned)
    __shared__ unsigned short Pl[4][16][72];  // per-wave P tile [q][key]

    const int tid = threadIdx.x;
    const int lane = tid & 63;
    const int w = tid >> 6;
    const int i16 = lane & 15, g = lane >> 4;

    const int qc = blockIdx.x & 7;
    const int bh = blockIdx.x >> 3;
    const unsigned short* Qp = qkv + (size_t)bh * NT * ND;
    const unsigned short* Kp = qkv + (size_t)NQTOT + (size_t)bh * NT * ND;
    const unsigned short* Vp = qkv + (size_t)2 * NQTOT + (size_t)bh * NT * ND;
    const int qbase = qc * 64 + w * 16;

    // Q fragment held in registers for the whole kernel (A-side: row = lane&15)
    const short8 qf = *reinterpret_cast<const short8*>(&Qp[(qbase + i16) * ND + g * 8]);

    const f32x4 z4 = {0.f, 0.f, 0.f, 0.f};
    f32x4 O0 = z4, O1 = z4;             // d 0..15 and 16..31, rows = g*4+r
    float m_[4], l_[4];
#pragma unroll
    for (int r = 0; r < 4; r++) { m_[r] = -3e38f; l_[r] = 0.f; }

    const int srow = tid >> 2;   // 0..63: key row for staging
    const int scr = tid & 3;     // d-chunk
    const float scale = 0.17677669529663687f;   // 1/sqrt(32)

    for (int kt = 0; kt <= qc; ++kt) {
        __syncthreads();
        // stage K tile [64][40]
        *reinterpret_cast<short8*>(&Kl[srow][scr * 8]) =
            *reinterpret_cast<const short8*>(&Kp[(kt * 64 + srow) * ND + scr * 8]);
        // stage V transposed: Vt[d][key]
        {
            short8 v = *reinterpret_cast<const short8*>(&Vp[(kt * 64 + srow) * ND + scr * 8]);
#pragma unroll
            for (int j = 0; j < 8; j++) Vt[scr * 8 + j][srow] = (unsigned short)v[j];
        }
        __syncthreads();

        // S = Q K^T (4 sub-tiles of 16 keys)
        float s[4][4];
#pragma unroll
        for (int kc = 0; kc < 4; kc++) {
            short8 kf = *reinterpret_cast<const short8*>(&Kl[kc * 16 + i16][g * 8]);
            f32x4 sv = __builtin_amdgcn_mfma_f32_16x16x32_bf16(qf, kf, z4, 0, 0, 0);
            const int key = kt * 64 + kc * 16 + i16;
#pragma unroll
            for (int r = 0; r < 4; r++) {
                const int q = qbase + g * 4 + r;
                s[kc][r] = (key <= q) ? sv[r] * scale : -3e38f;
            }
        }

        // online softmax (row spread across 16 lanes; rows = g*4+r)
#pragma unroll
        for (int r = 0; r < 4; r++) {
            float tm = fmaxf(fmaxf(s[0][r], s[1][r]), fmaxf(s[2][r], s[3][r]));
            for (int d = 1; d < 16; d <<= 1) tm = fmaxf(tm, __shfl_xor(tm, d, 64));
            const float nm = fmaxf(m_[r], tm);
            const float f = __expf(m_[r] - nm);
            m_[r] = nm;
            float p0 = __expf(s[0][r] - nm);
            float p1 = __expf(s[1][r] - nm);
            float p2 = __expf(s[2][r] - nm);
            float p3 = __expf(s[3][r] - nm);
            float ps = p0 + p1 + p2 + p3;
            for (int d = 1; d < 16; d <<= 1) ps += __shfl_xor(ps, d, 64);
            l_[r] = l_[r] * f + ps;
            O0[r] *= f; O1[r] *= f;
            Pl[w][g * 4 + r][0 * 16 + i16] = f2bf(p0);
            Pl[w][g * 4 + r][1 * 16 + i16] = f2bf(p1);
            Pl[w][g * 4 + r][2 * 16 + i16] = f2bf(p2);
            Pl[w][g * 4 + r][3 * 16 + i16] = f2bf(p3);
        }
        __syncthreads();   // make P writes visible to PV fragment reads (cross-lane)

        // PV: O += P[16q x 64key] * V[64key x 32d]
#pragma unroll
        for (int kc2 = 0; kc2 < 2; kc2++) {
            short8 pf = *reinterpret_cast<const short8*>(&Pl[w][i16][kc2 * 32 + g * 8]);
            short8 v0 = *reinterpret_cast<const short8*>(&Vt[i16][kc2 * 32 + g * 8]);
            short8 v1 = *reinterpret_cast<const short8*>(&Vt[16 + i16][kc2 * 32 + g * 8]);
            O0 = __builtin_amdgcn_mfma_f32_16x16x32_bf16(pf, v0, O0, 0, 0, 0);
            O1 = __builtin_amdgcn_mfma_f32_16x16x32_bf16(pf, v1, O1, 0, 0, 0);
        }
    }

    // epilogue: Ob is [B,T,C] bf16 (rows=token, cols=h*32+d) feeding proj GEMM
    const int b = bh >> 3, h = bh & 7;
#pragma unroll
    for (int r = 0; r < 4; r++) {
        const float inv = 1.f / l_[r];
        const int t = qbase + g * 4 + r;
        const size_t base = ((size_t)(b * NT + t)) * NC + h * 32;
        Ob[base + i16] = f2bf(O0[r] * inv);
        Ob[base + 16 + i16] = f2bf(O1[r] * inv);
    }
}

// ---------------- launch ----------------
extern "C" void kernel_launch(void* const* d_in, const int* in_sizes, int n_in,
                              void* d_out, int out_size, void* d_ws, size_t ws_size,
                              hipStream_t stream) {
    const float* x     = (const float*)d_in[0];
    const float* Wqkv  = (const float*)d_in[1];
    const float* bqkv  = (const float*)d_in[2];
    const float* Wproj = (const float*)d_in[3];
    const float* bproj = (const float*)d_in[4];
    float* out = (float*)d_out;

    // workspace layout (bf16 elements), total ~42.5 MB
    unsigned short* Xb     = (unsigned short*)d_ws;                  // 16384*256
    unsigned short* WqkvT  = Xb + (size_t)16384 * 256;               // 768*256
    unsigned short* WprojT = WqkvT + (size_t)768 * 256;              // 256*256
    unsigned short* QKV    = WprojT + (size_t)256 * 256;             // 3 * NQTOT
    unsigned short* Ob     = QKV + (size_t)3 * NQTOT;                // 16384*256

    k_cvt_x<<<4096, 256, 0, stream>>>(x, Xb, (16384 * 256) / 4);
    k_cvt_wT<<<(768 * 256) / 256, 256, 0, stream>>>(Wqkv, WqkvT, 256, 768);
    k_cvt_wT<<<(256 * 256) / 256, 256, 0, stream>>>(Wproj, WprojT, 256, 256);

    k_gemm<0><<<128 * 6, 256, 0, stream>>>(Xb, WqkvT, bqkv, QKV, nullptr, 16384, 768, 256);
    k_attn<<<2048, 256, 0, stream>>>(QKV, Ob);
    k_gemm<1><<<128 * 2, 256, 0, stream>>>(Ob, WprojT, bproj, nullptr, out, 16384, 256, 256);
}

// Round 2
// 162.112 us; speedup vs baseline: 1.0220x; 1.0220x over previous
//
#include <hip/hip_runtime.h>
#include <stdint.h>
#include <stddef.h>

// Problem constants (B=32, T=512, C=256, H=8, D=32)
#define NB 32
#define NT 512
#define NC 256
#define NH 8
#define ND 32
#define NQTOT (NB*NH*NT*ND)   // 4194304 elements per Q/K/V tensor

typedef __attribute__((ext_vector_type(8))) short short8;
typedef __attribute__((ext_vector_type(4))) float f32x4;

// f32 -> bf16 round-to-nearest-even
__device__ __forceinline__ unsigned short f2bf(float f) {
    union { float f; unsigned u; } x; x.f = f;
    unsigned r = (x.u + 0x7FFFu + ((x.u >> 16) & 1u)) >> 16;
    return (unsigned short)r;
}

// w: [K][N] f32  ->  wt: [N][K] bf16   (small, L2-resident)
__global__ __launch_bounds__(256) void k_cvt_wT(const float* __restrict__ w,
                                                unsigned short* __restrict__ wt, int K, int N) {
    int idx = blockIdx.x * 256 + threadIdx.x;
    if (idx < K * N) {
        int n = idx / K;
        int k = idx - n * K;
        wt[idx] = f2bf(w[(size_t)k * N + n]);
    }
}

// ---------------- bf16 MFMA GEMM: C = A[M,K] * Bt[N,K]^T + bias ----------------
// 128x128 tile, BK=32, double-buffered LDS, 1 barrier/iter (T14 load-early/store-late).
// EPI 0: A is f32 (x), fused cvt; scatter to Q/K/V [B,H,T,D] bf16.
// EPI 1: A is bf16; f32 out [M,N] + bias.
template <int EPI>
__global__ __launch_bounds__(256) void k_gemm(const void* __restrict__ Av,
                                              const unsigned short* __restrict__ Bt,
                                              const float* __restrict__ bias,
                                              unsigned short* __restrict__ qkv,
                                              float* __restrict__ outf,
                                              int M, int N, int K) {
    __shared__ unsigned short Al[2][128][40];   // +8 pad: frag reads ~2-way, rows 16B-aligned
    __shared__ unsigned short Bl[2][128][40];

    const int tid = threadIdx.x;
    const int lane = tid & 63;
    const int w = tid >> 6;
    const int wm = w >> 1, wn = w & 1;
    const int i16 = lane & 15, g = lane >> 4;

    const int nbm = M >> 7;
    const int bm = blockIdx.x % nbm;
    const int bn = blockIdx.x / nbm;
    const int m0 = bm << 7, n0 = bn << 7;

    const float* Af = (const float*)Av;
    const unsigned short* Ab = (const unsigned short*)Av;

    f32x4 acc[4][4];
    const f32x4 z4 = {0.f, 0.f, 0.f, 0.f};
#pragma unroll
    for (int a = 0; a < 4; a++)
#pragma unroll
        for (int b = 0; b < 4; b++) acc[a][b] = z4;

    const int row0 = tid >> 2;   // 0..63
    const int cr = tid & 3;      // k-chunk within row (8 elems)

    // staging registers
    float4 fa[2][2];
    short8 sa[2];
    short8 sb[2];

    auto LOAD = [&](int k0) {
#pragma unroll
        for (int h = 0; h < 2; ++h) {
            const int row = row0 + h * 64;
            if (EPI == 0) {
                const float* p = &Af[(size_t)(m0 + row) * K + k0 + cr * 8];
                fa[h][0] = *reinterpret_cast<const float4*>(p);
                fa[h][1] = *reinterpret_cast<const float4*>(p + 4);
            } else {
                sa[h] = *reinterpret_cast<const short8*>(&Ab[(size_t)(m0 + row) * K + k0 + cr * 8]);
            }
            sb[h] = *reinterpret_cast<const short8*>(&Bt[(size_t)(n0 + row) * K + k0 + cr * 8]);
        }
    };
    auto STORE = [&](int buf) {
#pragma unroll
        for (int h = 0; h < 2; ++h) {
            const int row = row0 + h * 64;
            if (EPI == 0) {
                short8 t;
                t[0] = (short)f2bf(fa[h][0].x); t[1] = (short)f2bf(fa[h][0].y);
                t[2] = (short)f2bf(fa[h][0].z); t[3] = (short)f2bf(fa[h][0].w);
                t[4] = (short)f2bf(fa[h][1].x); t[5] = (short)f2bf(fa[h][1].y);
                t[6] = (short)f2bf(fa[h][1].z); t[7] = (short)f2bf(fa[h][1].w);
                *reinterpret_cast<short8*>(&Al[buf][row][cr * 8]) = t;
            } else {
                *reinterpret_cast<short8*>(&Al[buf][row][cr * 8]) = sa[h];
            }
            *reinterpret_cast<short8*>(&Bl[buf][row][cr * 8]) = sb[h];
        }
    };

    LOAD(0);
    STORE(0);
    __syncthreads();

    const int nk = K >> 5;
    for (int it = 0; it < nk; ++it) {
        const int cur = it & 1;
        if (it + 1 < nk) LOAD((it + 1) << 5);

        short8 af[4], bf[4];
#pragma unroll
        for (int mi = 0; mi < 4; mi++)
            af[mi] = *reinterpret_cast<const short8*>(&Al[cur][wm * 64 + mi * 16 + i16][g * 8]);
#pragma unroll
        for (int ni = 0; ni < 4; ni++)
            bf[ni] = *reinterpret_cast<const short8*>(&Bl[cur][wn * 64 + ni * 16 + i16][g * 8]);
#pragma unroll
        for (int mi = 0; mi < 4; mi++)
#pragma unroll
            for (int ni = 0; ni < 4; ni++)
                acc[mi][ni] = __builtin_amdgcn_mfma_f32_16x16x32_bf16(af[mi], bf[ni], acc[mi][ni], 0, 0, 0);

        if (it + 1 < nk) STORE(cur ^ 1);
        __syncthreads();
    }

    // epilogue: C/D layout col=lane&15, row=(lane>>4)*4+reg  [verified m89]
#pragma unroll
    for (int mi = 0; mi < 4; mi++) {
#pragma unroll
        for (int ni = 0; ni < 4; ni++) {
            const int col = n0 + wn * 64 + ni * 16 + i16;
            const float bv = bias[col];
#pragma unroll
            for (int r = 0; r < 4; r++) {
                const int rowg = m0 + wm * 64 + mi * 16 + g * 4 + r;
                const float v = acc[mi][ni][r] + bv;
                if (EPI == 0) {
                    const int which = col >> 8;
                    const int cc = col & 255;
                    const int h = cc >> 5, d = cc & 31;
                    const int bb = rowg >> 9, t = rowg & 511;
                    qkv[(size_t)which * NQTOT +
                        ((((size_t)bb * NH + h) * NT + t) * ND) + d] = f2bf(v);
                } else {
                    outf[(size_t)rowg * N + col] = v;
                }
            }
        }
    }
}

// ---------------- causal flash attention ----------------
// One block = (b,h, 128 q-rows); 4 waves x 32 q-rows (2 frags). K-tiles of 64 keys.
// K frags direct from global (L2), prefetched 1 tile ahead.
// V double-buffered in LDS with XOR swizzle (conflict-free transpose), 1 barrier/tile.
__global__ __launch_bounds__(256) void k_attn(const unsigned short* __restrict__ qkv,
                                              unsigned short* __restrict__ Ob) {
    __shared__ unsigned short Vt[2][32][64];  // [buf][d][swizzled key col]
    __shared__ unsigned short Pl[4][16][72];  // per-wave P tile [q][key]

    const int tid = threadIdx.x;
    const int lane = tid & 63;
    const int w = tid >> 6;
    const int i16 = lane & 15, g = lane >> 4;

    const int qc = blockIdx.x & 3;
    const int bh = blockIdx.x >> 2;
    const unsigned short* Qp = qkv + (size_t)bh * NT * ND;
    const unsigned short* Kp = qkv + (size_t)NQTOT + (size_t)bh * NT * ND;
    const unsigned short* Vp = qkv + (size_t)2 * NQTOT + (size_t)bh * NT * ND;
    const int qwave = qc * 128 + w * 32;

    // Q fragments (A-side: row = lane&15, k contiguous) — held all kernel
    short8 qf[2];
    qf[0] = *reinterpret_cast<const short8*>(&Qp[(qwave + i16) * ND + g * 8]);
    qf[1] = *reinterpret_cast<const short8*>(&Qp[(qwave + 16 + i16) * ND + g * 8]);

    const f32x4 z4 = {0.f, 0.f, 0.f, 0.f};
    f32x4 O[2][2];                 // [sub][d-half]; rows = g*4+r
    float m_[2][4], l_[2][4];
#pragma unroll
    for (int s = 0; s < 2; s++) {
        O[s][0] = z4; O[s][1] = z4;
#pragma unroll
        for (int r = 0; r < 4; r++) { m_[s][r] = -3e38f; l_[s][r] = 0.f; }
    }

    const int srow = tid >> 2;   // key within tile (staging)
    const int scr = tid & 3;     // d-chunk (staging)
    const int ktmax = 2 * qc + 1;
    const float scale = 0.17677669529663687f;   // 1/sqrt(32)

    // prologue: stage V tile 0 (swizzled transpose)
    {
        short8 v = *reinterpret_cast<const short8*>(&Vp[srow * ND + scr * 8]);
#pragma unroll
        for (int j = 0; j < 8; j++) {
            const int swz = j ^ (scr << 1);                    // (d&7)^(((d>>3)&3)<<1)
            Vt[0][scr * 8 + j][(srow & 7) + 8 * ((srow >> 3) ^ swz)] = (unsigned short)v[j];
        }
    }
    // K fragments for tile 0 (B-side: row = key, k contiguous) — direct global
    short8 kr[4];
#pragma unroll
    for (int kc = 0; kc < 4; kc++)
        kr[kc] = *reinterpret_cast<const short8*>(&Kp[(kc * 16 + i16) * ND + g * 8]);
    __syncthreads();

    for (int kt = 0; kt <= ktmax; ++kt) {
        const int cur = kt & 1;
        const bool haveNext = (kt < ktmax);

        // T14: issue next-tile loads first (latency hides under compute)
        short8 vnx, kn[4];
        if (haveNext) {
            vnx = *reinterpret_cast<const short8*>(&Vp[((kt + 1) * 64 + srow) * ND + scr * 8]);
#pragma unroll
            for (int kc = 0; kc < 4; kc++)
                kn[kc] = *reinterpret_cast<const short8*>(
                    &Kp[((kt + 1) * 64 + kc * 16 + i16) * ND + g * 8]);
        }

        if (kt * 64 <= qwave + 31) {   // tile not fully masked for this wave
            // hoist V fragments (B-side: row = d, swizzled key groups)
            short8 vf[2][2];
#pragma unroll
            for (int kc2 = 0; kc2 < 2; kc2++)
#pragma unroll
                for (int dh = 0; dh < 2; dh++) {
                    const int dd = dh * 16 + i16;
                    const int swzd = (dd & 7) ^ (((dd >> 3) & 3) << 1);
                    vf[kc2][dh] = *reinterpret_cast<const short8*>(
                        &Vt[cur][dd][8 * ((kc2 * 4 + g) ^ swzd)]);
                }

#pragma unroll
            for (int sub = 0; sub < 2; ++sub) {
                // S = Q K^T
                float s[4][4];
#pragma unroll
                for (int kc = 0; kc < 4; kc++) {
                    f32x4 sv = __builtin_amdgcn_mfma_f32_16x16x32_bf16(qf[sub], kr[kc], z4, 0, 0, 0);
                    const int key = kt * 64 + kc * 16 + i16;
#pragma unroll
                    for (int r = 0; r < 4; r++) {
                        const int q = qwave + sub * 16 + g * 4 + r;
                        s[kc][r] = (key <= q) ? sv[r] * scale : -3e38f;
                    }
                }
                // online softmax (row spread across 16 lanes)
#pragma unroll
                for (int r = 0; r < 4; r++) {
                    float tm = fmaxf(fmaxf(s[0][r], s[1][r]), fmaxf(s[2][r], s[3][r]));
#pragma unroll
                    for (int d = 1; d < 16; d <<= 1) tm = fmaxf(tm, __shfl_xor(tm, d, 64));
                    const float nm = fmaxf(m_[sub][r], tm);
                    const float fr = __expf(m_[sub][r] - nm);
                    m_[sub][r] = nm;
                    const float p0 = __expf(s[0][r] - nm);
                    const float p1 = __expf(s[1][r] - nm);
                    const float p2 = __expf(s[2][r] - nm);
                    const float p3 = __expf(s[3][r] - nm);
                    float ps = p0 + p1 + p2 + p3;
#pragma unroll
                    for (int d = 1; d < 16; d <<= 1) ps += __shfl_xor(ps, d, 64);
                    l_[sub][r] = l_[sub][r] * fr + ps;
                    O[sub][0][r] *= fr; O[sub][1][r] *= fr;
                    Pl[w][g * 4 + r][ 0 + i16] = f2bf(p0);
                    Pl[w][g * 4 + r][16 + i16] = f2bf(p1);
                    Pl[w][g * 4 + r][32 + i16] = f2bf(p2);
                    Pl[w][g * 4 + r][48 + i16] = f2bf(p3);
                }
                // P is per-wave: wave-local LDS fence (rule #18: fence + sched_barrier)
                asm volatile("s_waitcnt lgkmcnt(0)" ::: "memory");
                __builtin_amdgcn_sched_barrier(0);
                // PV: O += P[16q x 64k] * V[64k x 32d]
#pragma unroll
                for (int kc2 = 0; kc2 < 2; kc2++) {
                    short8 pf = *reinterpret_cast<const short8*>(&Pl[w][i16][kc2 * 32 + g * 8]);
                    O[sub][0] = __builtin_amdgcn_mfma_f32_16x16x32_bf16(pf, vf[kc2][0], O[sub][0], 0, 0, 0);
                    O[sub][1] = __builtin_amdgcn_mfma_f32_16x16x32_bf16(pf, vf[kc2][1], O[sub][1], 0, 0, 0);
                }
            }
        }

        // late-write next V tile into the other buffer; roll K regs
        if (haveNext) {
#pragma unroll
            for (int j = 0; j < 8; j++) {
                const int swz = j ^ (scr << 1);
                Vt[cur ^ 1][scr * 8 + j][(srow & 7) + 8 * ((srow >> 3) ^ swz)] = (unsigned short)vnx[j];
            }
#pragma unroll
            for (int kc = 0; kc < 4; kc++) kr[kc] = kn[kc];
        }
        __syncthreads();
    }

    // epilogue: Ob is [B,T,C] bf16 feeding proj GEMM
    const int b = bh >> 3, h = bh & 7;
#pragma unroll
    for (int sub = 0; sub < 2; ++sub)
#pragma unroll
        for (int r = 0; r < 4; r++) {
            const float inv = 1.f / l_[sub][r];
            const int t = qwave + sub * 16 + g * 4 + r;
            const size_t base = ((size_t)(b * NT + t)) * NC + h * 32;
            Ob[base + i16] = f2bf(O[sub][0][r] * inv);
            Ob[base + 16 + i16] = f2bf(O[sub][1][r] * inv);
        }
}

// ---------------- launch ----------------
extern "C" void kernel_launch(void* const* d_in, const int* in_sizes, int n_in,
                              void* d_out, int out_size, void* d_ws, size_t ws_size,
                              hipStream_t stream) {
    const float* x     = (const float*)d_in[0];
    const float* Wqkv  = (const float*)d_in[1];
    const float* bqkv  = (const float*)d_in[2];
    const float* Wproj = (const float*)d_in[3];
    const float* bproj = (const float*)d_in[4];
    float* out = (float*)d_out;

    // workspace layout (bf16 elements)
    unsigned short* WqkvT  = (unsigned short*)d_ws;                  // 768*256
    unsigned short* WprojT = WqkvT + (size_t)768 * 256;              // 256*256
    unsigned short* QKV    = WprojT + (size_t)256 * 256;             // 3 * NQTOT
    unsigned short* Ob     = QKV + (size_t)3 * NQTOT;                // 16384*256

    k_cvt_wT<<<(768 * 256) / 256, 256, 0, stream>>>(Wqkv, WqkvT, 256, 768);
    k_cvt_wT<<<(256 * 256) / 256, 256, 0, stream>>>(Wproj, WprojT, 256, 256);

    k_gemm<0><<<128 * 6, 256, 0, stream>>>(x, WqkvT, bqkv, QKV, nullptr, 16384, 768, 256);
    k_attn<<<1024, 256, 0, stream>>>(QKV, Ob);
    k_gemm<1><<<128 * 2, 256, 0, stream>>>(Ob, WprojT, bproj, nullptr, out, 16384, 256, 256);
}

// Round 3
// 142.390 us; speedup vs baseline: 1.1636x; 1.1385x over previous
//
#include <hip/hip_runtime.h>
#include <stdint.h>
#include <stddef.h>

// Problem constants (B=32, T=512, C=256, H=8, D=32)
#define NB 32
#define NT 512
#define NC 256
#define NH 8
#define ND 32
#define NQTOT (NB*NH*NT*ND)   // 4194304 elements per Q/K/V tensor

typedef __attribute__((ext_vector_type(8))) short short8;
typedef __attribute__((ext_vector_type(4))) float f32x4;

// f32 -> bf16 round-to-nearest-even
__device__ __forceinline__ unsigned short f2bf(float f) {
    union { float f; unsigned u; } x; x.f = f;
    unsigned r = (x.u + 0x7FFFu + ((x.u >> 16) & 1u)) >> 16;
    return (unsigned short)r;
}

// w: [K][N] f32 -> wt: [N][K] bf16 via 32x32 LDS tile (coalesced both sides)
__global__ __launch_bounds__(256) void k_cvt_wT(const float* __restrict__ w,
                                                unsigned short* __restrict__ wt, int K, int N) {
    __shared__ float tile[32][33];
    const int tx = threadIdx.x & 31;
    const int ty = threadIdx.x >> 5;      // 0..7
    const int n0 = blockIdx.x * 32;
    const int k0 = blockIdx.y * 32;
#pragma unroll
    for (int dy = 0; dy < 4; ++dy) {
        const int k = ty + dy * 8;
        tile[k][tx] = w[(size_t)(k0 + k) * N + n0 + tx];
    }
    __syncthreads();
#pragma unroll
    for (int dy = 0; dy < 4; ++dy) {
        const int n = ty + dy * 8;
        wt[(size_t)(n0 + n) * K + k0 + tx] = f2bf(tile[tx][n]);
    }
}

// ---------------- bf16 MFMA GEMM: C = A[M,K] * Bt[N,K]^T + bias ----------------
// 128x128 tile, BK=32, double-buffered LDS, 1 barrier/iter (T14 load-early/store-late).
// EPI 0: A is f32 (x), fused cvt; scatter to Q/K/V [B,H,T,D] bf16.
// EPI 1: A is bf16; f32 out [M,N] + bias.
template <int EPI>
__global__ __launch_bounds__(256) void k_gemm(const void* __restrict__ Av,
                                              const unsigned short* __restrict__ Bt,
                                              const float* __restrict__ bias,
                                              unsigned short* __restrict__ qkv,
                                              float* __restrict__ outf,
                                              int M, int N, int K) {
    __shared__ unsigned short Al[2][128][40];
    __shared__ unsigned short Bl[2][128][40];

    const int tid = threadIdx.x;
    const int lane = tid & 63;
    const int w = tid >> 6;
    const int wm = w >> 1, wn = w & 1;
    const int i16 = lane & 15, g = lane >> 4;

    const int nbm = M >> 7;
    const int bm = blockIdx.x % nbm;
    const int bn = blockIdx.x / nbm;
    const int m0 = bm << 7, n0 = bn << 7;

    const float* Af = (const float*)Av;
    const unsigned short* Ab = (const unsigned short*)Av;

    f32x4 acc[4][4];
    const f32x4 z4 = {0.f, 0.f, 0.f, 0.f};
#pragma unroll
    for (int a = 0; a < 4; a++)
#pragma unroll
        for (int b = 0; b < 4; b++) acc[a][b] = z4;

    const int row0 = tid >> 2;
    const int cr = tid & 3;

    float4 fa[2][2];
    short8 sa[2];
    short8 sb[2];

    auto LOAD = [&](int k0) {
#pragma unroll
        for (int h = 0; h < 2; ++h) {
            const int row = row0 + h * 64;
            if (EPI == 0) {
                const float* p = &Af[(size_t)(m0 + row) * K + k0 + cr * 8];
                fa[h][0] = *reinterpret_cast<const float4*>(p);
                fa[h][1] = *reinterpret_cast<const float4*>(p + 4);
            } else {
                sa[h] = *reinterpret_cast<const short8*>(&Ab[(size_t)(m0 + row) * K + k0 + cr * 8]);
            }
            sb[h] = *reinterpret_cast<const short8*>(&Bt[(size_t)(n0 + row) * K + k0 + cr * 8]);
        }
    };
    auto STORE = [&](int buf) {
#pragma unroll
        for (int h = 0; h < 2; ++h) {
            const int row = row0 + h * 64;
            if (EPI == 0) {
                short8 t;
                t[0] = (short)f2bf(fa[h][0].x); t[1] = (short)f2bf(fa[h][0].y);
                t[2] = (short)f2bf(fa[h][0].z); t[3] = (short)f2bf(fa[h][0].w);
                t[4] = (short)f2bf(fa[h][1].x); t[5] = (short)f2bf(fa[h][1].y);
                t[6] = (short)f2bf(fa[h][1].z); t[7] = (short)f2bf(fa[h][1].w);
                *reinterpret_cast<short8*>(&Al[buf][row][cr * 8]) = t;
            } else {
                *reinterpret_cast<short8*>(&Al[buf][row][cr * 8]) = sa[h];
            }
            *reinterpret_cast<short8*>(&Bl[buf][row][cr * 8]) = sb[h];
        }
    };

    LOAD(0);
    STORE(0);
    __syncthreads();

    const int nk = K >> 5;
    for (int it = 0; it < nk; ++it) {
        const int cur = it & 1;
        if (it + 1 < nk) LOAD((it + 1) << 5);

        short8 af[4], bf[4];
#pragma unroll
        for (int mi = 0; mi < 4; mi++)
            af[mi] = *reinterpret_cast<const short8*>(&Al[cur][wm * 64 + mi * 16 + i16][g * 8]);
#pragma unroll
        for (int ni = 0; ni < 4; ni++)
            bf[ni] = *reinterpret_cast<const short8*>(&Bl[cur][wn * 64 + ni * 16 + i16][g * 8]);
#pragma unroll
        for (int mi = 0; mi < 4; mi++)
#pragma unroll
            for (int ni = 0; ni < 4; ni++)
                acc[mi][ni] = __builtin_amdgcn_mfma_f32_16x16x32_bf16(af[mi], bf[ni], acc[mi][ni], 0, 0, 0);

        if (it + 1 < nk) STORE(cur ^ 1);
        __syncthreads();
    }

    // epilogue: C/D layout col=lane&15, row=(lane>>4)*4+reg  [verified m89]
#pragma unroll
    for (int mi = 0; mi < 4; mi++) {
#pragma unroll
        for (int ni = 0; ni < 4; ni++) {
            const int col = n0 + wn * 64 + ni * 16 + i16;
            const float bv = bias[col];
#pragma unroll
            for (int r = 0; r < 4; r++) {
                const int rowg = m0 + wm * 64 + mi * 16 + g * 4 + r;
                const float v = acc[mi][ni][r] + bv;
                if (EPI == 0) {
                    const int which = col >> 8;
                    const int cc = col & 255;
                    const int h = cc >> 5, d = cc & 31;
                    const int bb = rowg >> 9, t = rowg & 511;
                    qkv[(size_t)which * NQTOT +
                        ((((size_t)bb * NH + h) * NT + t) * ND) + d] = f2bf(v);
                } else {
                    outf[(size_t)rowg * N + col] = v;
                }
            }
        }
    }
}

// ---------------- causal flash attention (swapped-operand form) ----------------
// One block = (b,h, 64 q-rows); 4 waves x 16 q-rows. K-tiles of 64 keys.
// S^T = mfma(Kfrag, Qfrag): lane holds one q (=lane&15), 16 keys in regs ->
// softmax = in-lane tree + 2 shfls. O^T = mfma(Vtfrag, Ptfrag).
// K frags direct from global (prefetched); V double-buffered swizzled LDS; 1 barrier/tile.
__global__ __launch_bounds__(256) void k_attn(const unsigned short* __restrict__ qkv,
                                              unsigned short* __restrict__ Ob) {
    __shared__ unsigned short Vt[2][32][64];  // [buf][d][swizzled key col]
    __shared__ unsigned short Pl[4][16][72];  // per-wave P^T source: [q][key]

    const int tid = threadIdx.x;
    const int lane = tid & 63;
    const int w = tid >> 6;
    const int i16 = lane & 15, g = lane >> 4;

    const int qc = blockIdx.x & 7;
    const int bh = blockIdx.x >> 3;
    const unsigned short* Qp = qkv + (size_t)bh * NT * ND;
    const unsigned short* Kp = qkv + (size_t)NQTOT + (size_t)bh * NT * ND;
    const unsigned short* Vp = qkv + (size_t)2 * NQTOT + (size_t)bh * NT * ND;
    const int qwave = qc * 64 + w * 16;
    const int q = qwave + i16;              // this lane's q row

    // Q fragment (B-side: row=lane&15 -> q, k contiguous g*8)
    const short8 qf = *reinterpret_cast<const short8*>(&Qp[q * ND + g * 8]);

    const f32x4 z4 = {0.f, 0.f, 0.f, 0.f};
    f32x4 O0 = z4, O1 = z4;                 // O^T: d = dh*16+g*4+r, col q=i16
    float m_ = -3e38f, l_ = 0.f;

    const int srow = tid >> 2;   // key within tile (staging)
    const int scr = tid & 3;     // d-chunk (staging)
    // scale with ln2 folded in: S_log2 = S * (1/sqrt(32) * log2(e))
    const float scale2 = 0.17677669529663687f * 1.4426950408889634f;

    // prologue: stage V tile 0 (swizzled transpose) + K frags tile 0
    {
        short8 v = *reinterpret_cast<const short8*>(&Vp[srow * ND + scr * 8]);
#pragma unroll
        for (int j = 0; j < 8; j++) {
            const int swz = j ^ (scr << 1);   // (d&7)^(((d>>3)&3)<<1)
            Vt[0][scr * 8 + j][(srow & 7) + 8 * ((srow >> 3) ^ swz)] = (unsigned short)v[j];
        }
    }
    short8 kr[4];
#pragma unroll
    for (int kc = 0; kc < 4; kc++)
        kr[kc] = *reinterpret_cast<const short8*>(&Kp[(kc * 16 + i16) * ND + g * 8]);
    __syncthreads();

    for (int kt = 0; kt <= qc; ++kt) {
        const int cur = kt & 1;
        const bool haveNext = (kt < qc);

        // T14: issue next-tile loads first (latency hides under compute)
        short8 vnx, kn[4];
        if (haveNext) {
            vnx = *reinterpret_cast<const short8*>(&Vp[((kt + 1) * 64 + srow) * ND + scr * 8]);
#pragma unroll
            for (int kc = 0; kc < 4; kc++)
                kn[kc] = *reinterpret_cast<const short8*>(
                    &Kp[((kt + 1) * 64 + kc * 16 + i16) * ND + g * 8]);
        }

        // hoist V fragments (A-side for PV: row=d, keys g*8.. swizzled groups)
        short8 vf[2][2];
#pragma unroll
        for (int kc2 = 0; kc2 < 2; kc2++)
#pragma unroll
            for (int dh = 0; dh < 2; dh++) {
                const int dd = dh * 16 + i16;
                const int swzd = (dd & 7) ^ (((dd >> 3) & 3) << 1);
                vf[kc2][dh] = *reinterpret_cast<const short8*>(
                    &Vt[cur][dd][8 * ((kc2 * 4 + g) ^ swzd)]);
            }

        // S^T = K Q^T: lane holds q=i16, keys kc*16 + g*4 + r
        const bool diag = (kt == qc);
        float s[4][4];
#pragma unroll
        for (int kc = 0; kc < 4; kc++) {
            if (!diag || kc <= w) {
                f32x4 sv = __builtin_amdgcn_mfma_f32_16x16x32_bf16(kr[kc], qf, z4, 0, 0, 0);
                if (diag && kc == w) {
#pragma unroll
                    for (int r = 0; r < 4; r++)
                        s[kc][r] = (g * 4 + r <= i16) ? sv[r] * scale2 : -3e38f;
                } else {
#pragma unroll
                    for (int r = 0; r < 4; r++) s[kc][r] = sv[r] * scale2;
                }
            } else {
#pragma unroll
                for (int r = 0; r < 4; r++) s[kc][r] = -3e38f;
            }
        }

        // online softmax: in-lane tree over 16 + 2 shfls across g-groups
        float tm = fmaxf(fmaxf(fmaxf(s[0][0], s[0][1]), fmaxf(s[0][2], s[0][3])),
                         fmaxf(fmaxf(s[1][0], s[1][1]), fmaxf(s[1][2], s[1][3])));
        tm = fmaxf(tm, fmaxf(fmaxf(fmaxf(s[2][0], s[2][1]), fmaxf(s[2][2], s[2][3])),
                             fmaxf(fmaxf(s[3][0], s[3][1]), fmaxf(s[3][2], s[3][3]))));
        tm = fmaxf(tm, __shfl_xor(tm, 16, 64));
        tm = fmaxf(tm, __shfl_xor(tm, 32, 64));
        const float nm = fmaxf(m_, tm);
        const float fr = exp2f(m_ - nm);
        m_ = nm;
        float ps = 0.f;
#pragma unroll
        for (int kc = 0; kc < 4; kc++)
#pragma unroll
            for (int r = 0; r < 4; r++) {
                s[kc][r] = exp2f(s[kc][r] - nm);
                ps += s[kc][r];
            }
        ps += __shfl_xor(ps, 16, 64);
        ps += __shfl_xor(ps, 32, 64);
        l_ = l_ * fr + ps;
        O0 *= fr; O1 *= fr;

        // P^T write: per kc, keys g*4..g*4+3 are consecutive -> packed 8B store
#pragma unroll
        for (int kc = 0; kc < 4; kc++) {
            ushort4 pk;
            pk.x = f2bf(s[kc][0]); pk.y = f2bf(s[kc][1]);
            pk.z = f2bf(s[kc][2]); pk.w = f2bf(s[kc][3]);
            *reinterpret_cast<ushort4*>(&Pl[w][i16][kc * 16 + g * 4]) = pk;
        }
        // per-wave LDS fence (rule #18: fence + sched_barrier)
        asm volatile("s_waitcnt lgkmcnt(0)" ::: "memory");
        __builtin_amdgcn_sched_barrier(0);

        // O^T += V^T P^T  (A=vf rows=d, B=pf rows=q)
#pragma unroll
        for (int kc2 = 0; kc2 < 2; kc2++) {
            short8 pf = *reinterpret_cast<const short8*>(&Pl[w][i16][kc2 * 32 + g * 8]);
            O0 = __builtin_amdgcn_mfma_f32_16x16x32_bf16(vf[kc2][0], pf, O0, 0, 0, 0);
            O1 = __builtin_amdgcn_mfma_f32_16x16x32_bf16(vf[kc2][1], pf, O1, 0, 0, 0);
        }

        // late-write next V tile; roll K regs
        if (haveNext) {
#pragma unroll
            for (int j = 0; j < 8; j++) {
                const int swz = j ^ (scr << 1);
                Vt[cur ^ 1][scr * 8 + j][(srow & 7) + 8 * ((srow >> 3) ^ swz)] = (unsigned short)vnx[j];
            }
#pragma unroll
            for (int kc = 0; kc < 4; kc++) kr[kc] = kn[kc];
        }
        __syncthreads();
    }

    // epilogue: lane holds O^T for q=i16, d=dh*16+g*4+r -> packed 8B stores
    const int b = bh >> 3, h = bh & 7;
    const float inv = 1.f / l_;
    const size_t base = ((size_t)(b * NT + q)) * NC + h * 32;
    ushort4 o0, o1;
    o0.x = f2bf(O0[0] * inv); o0.y = f2bf(O0[1] * inv);
    o0.z = f2bf(O0[2] * inv); o0.w = f2bf(O0[3] * inv);
    o1.x = f2bf(O1[0] * inv); o1.y = f2bf(O1[1] * inv);
    o1.z = f2bf(O1[2] * inv); o1.w = f2bf(O1[3] * inv);
    *reinterpret_cast<ushort4*>(&Ob[base + g * 4]) = o0;
    *reinterpret_cast<ushort4*>(&Ob[base + 16 + g * 4]) = o1;
}

// ---------------- launch ----------------
extern "C" void kernel_launch(void* const* d_in, const int* in_sizes, int n_in,
                              void* d_out, int out_size, void* d_ws, size_t ws_size,
                              hipStream_t stream) {
    const float* x     = (const float*)d_in[0];
    const float* Wqkv  = (const float*)d_in[1];
    const float* bqkv  = (const float*)d_in[2];
    const float* Wproj = (const float*)d_in[3];
    const float* bproj = (const float*)d_in[4];
    float* out = (float*)d_out;

    unsigned short* WqkvT  = (unsigned short*)d_ws;                  // 768*256
    unsigned short* WprojT = WqkvT + (size_t)768 * 256;              // 256*256
    unsigned short* QKV    = WprojT + (size_t)256 * 256;             // 3 * NQTOT
    unsigned short* Ob     = QKV + (size_t)3 * NQTOT;                // 16384*256

    k_cvt_wT<<<dim3(24, 8), 256, 0, stream>>>(Wqkv, WqkvT, 256, 768);
    k_cvt_wT<<<dim3(8, 8), 256, 0, stream>>>(Wproj, WprojT, 256, 256);

    k_gemm<0><<<128 * 6, 256, 0, stream>>>(x, WqkvT, bqkv, QKV, nullptr, 16384, 768, 256);
    k_attn<<<2048, 256, 0, stream>>>(QKV, Ob);
    k_gemm<1><<<128 * 2, 256, 0, stream>>>(Ob, WprojT, bproj, nullptr, out, 16384, 256, 256);
}

// Round 4
// 129.471 us; speedup vs baseline: 1.2797x; 1.0998x over previous
//
#include <hip/hip_runtime.h>
#include <stdint.h>
#include <stddef.h>

// Problem constants (B=32, T=512, C=256, H=8, D=32)
#define NB 32
#define NT 512
#define NC 256
#define NH 8
#define ND 32
#define NQTOT (NB*NH*NT*ND)   // 4194304 elements per Q/K/V tensor

typedef __attribute__((ext_vector_type(8))) short short8;
typedef __attribute__((ext_vector_type(4))) float f32x4;

// f32 -> bf16 round-to-nearest-even
__device__ __forceinline__ unsigned short f2bf(float f) {
    union { float f; unsigned u; } x; x.f = f;
    unsigned r = (x.u + 0x7FFFu + ((x.u >> 16) & 1u)) >> 16;
    return (unsigned short)r;
}

// Both weight transposes in one launch: w [K=256][N] f32 -> wt [N][K] bf16.
// Blocks 0..191: Wqkv (N=768, 24x8 tiles); 192..255: Wproj (N=256, 8x8 tiles).
__global__ __launch_bounds__(256) void k_cvt_w2(const float* __restrict__ wqkv,
                                                unsigned short* __restrict__ wqkvT,
                                                const float* __restrict__ wproj,
                                                unsigned short* __restrict__ wprojT) {
    __shared__ float tile[32][33];
    int bid = blockIdx.x;
    const float* w; unsigned short* wt; int N, bx, by;
    if (bid < 192) { w = wqkv; wt = wqkvT; N = 768; bx = bid % 24; by = bid / 24; }
    else { bid -= 192; w = wproj; wt = wprojT; N = 256; bx = bid % 8; by = bid / 8; }
    const int K = 256;
    const int tx = threadIdx.x & 31;
    const int ty = threadIdx.x >> 5;      // 0..7
    const int n0 = bx * 32, k0 = by * 32;
#pragma unroll
    for (int dy = 0; dy < 4; ++dy)
        tile[ty + dy * 8][tx] = w[(size_t)(k0 + ty + dy * 8) * N + n0 + tx];
    __syncthreads();
#pragma unroll
    for (int dy = 0; dy < 4; ++dy)
        wt[(size_t)(n0 + ty + dy * 8) * K + k0 + tx] = f2bf(tile[tx][ty + dy * 8]);
}

// ---------------- bf16 MFMA GEMM: C = A[M,K] * Bt[N,K]^T + bias ----------------
// 128x128 tile, BK=32, double-buffered LDS, 1 barrier/iter (T14 load-early/store-late).
// EPI 0: A is f32 (x), fused cvt; scatter to Q/K/V [B,H,T,D] bf16.
// EPI 1: A is bf16; f32 out [M,N] + bias.
template <int EPI>
__global__ __launch_bounds__(256) void k_gemm(const void* __restrict__ Av,
                                              const unsigned short* __restrict__ Bt,
                                              const float* __restrict__ bias,
                                              unsigned short* __restrict__ qkv,
                                              float* __restrict__ outf,
                                              int M, int N, int K) {
    __shared__ unsigned short Al[2][128][40];
    __shared__ unsigned short Bl[2][128][40];

    const int tid = threadIdx.x;
    const int lane = tid & 63;
    const int w = tid >> 6;
    const int wm = w >> 1, wn = w & 1;
    const int i16 = lane & 15, g = lane >> 4;

    const int nbm = M >> 7;
    const int bm = blockIdx.x % nbm;
    const int bn = blockIdx.x / nbm;
    const int m0 = bm << 7, n0 = bn << 7;

    const float* Af = (const float*)Av;
    const unsigned short* Ab = (const unsigned short*)Av;

    f32x4 acc[4][4];
    const f32x4 z4 = {0.f, 0.f, 0.f, 0.f};
#pragma unroll
    for (int a = 0; a < 4; a++)
#pragma unroll
        for (int b = 0; b < 4; b++) acc[a][b] = z4;

    const int row0 = tid >> 2;
    const int cr = tid & 3;

    float4 fa[2][2];
    short8 sa[2];
    short8 sb[2];

    auto LOAD = [&](int k0) {
#pragma unroll
        for (int h = 0; h < 2; ++h) {
            const int row = row0 + h * 64;
            if (EPI == 0) {
                const float* p = &Af[(size_t)(m0 + row) * K + k0 + cr * 8];
                fa[h][0] = *reinterpret_cast<const float4*>(p);
                fa[h][1] = *reinterpret_cast<const float4*>(p + 4);
            } else {
                sa[h] = *reinterpret_cast<const short8*>(&Ab[(size_t)(m0 + row) * K + k0 + cr * 8]);
            }
            sb[h] = *reinterpret_cast<const short8*>(&Bt[(size_t)(n0 + row) * K + k0 + cr * 8]);
        }
    };
    auto STORE = [&](int buf) {
#pragma unroll
        for (int h = 0; h < 2; ++h) {
            const int row = row0 + h * 64;
            if (EPI == 0) {
                short8 t;
                t[0] = (short)f2bf(fa[h][0].x); t[1] = (short)f2bf(fa[h][0].y);
                t[2] = (short)f2bf(fa[h][0].z); t[3] = (short)f2bf(fa[h][0].w);
                t[4] = (short)f2bf(fa[h][1].x); t[5] = (short)f2bf(fa[h][1].y);
                t[6] = (short)f2bf(fa[h][1].z); t[7] = (short)f2bf(fa[h][1].w);
                *reinterpret_cast<short8*>(&Al[buf][row][cr * 8]) = t;
            } else {
                *reinterpret_cast<short8*>(&Al[buf][row][cr * 8]) = sa[h];
            }
            *reinterpret_cast<short8*>(&Bl[buf][row][cr * 8]) = sb[h];
        }
    };

    LOAD(0);
    STORE(0);
    __syncthreads();

    const int nk = K >> 5;
    for (int it = 0; it < nk; ++it) {
        const int cur = it & 1;
        if (it + 1 < nk) LOAD((it + 1) << 5);

        short8 af[4], bf[4];
#pragma unroll
        for (int mi = 0; mi < 4; mi++)
            af[mi] = *reinterpret_cast<const short8*>(&Al[cur][wm * 64 + mi * 16 + i16][g * 8]);
#pragma unroll
        for (int ni = 0; ni < 4; ni++)
            bf[ni] = *reinterpret_cast<const short8*>(&Bl[cur][wn * 64 + ni * 16 + i16][g * 8]);
#pragma unroll
        for (int mi = 0; mi < 4; mi++)
#pragma unroll
            for (int ni = 0; ni < 4; ni++)
                acc[mi][ni] = __builtin_amdgcn_mfma_f32_16x16x32_bf16(af[mi], bf[ni], acc[mi][ni], 0, 0, 0);

        if (it + 1 < nk) STORE(cur ^ 1);
        __syncthreads();
    }

    // epilogue: C/D layout col=lane&15, row=(lane>>4)*4+reg  [verified m89]
#pragma unroll
    for (int mi = 0; mi < 4; mi++) {
#pragma unroll
        for (int ni = 0; ni < 4; ni++) {
            const int col = n0 + wn * 64 + ni * 16 + i16;
            const float bv = bias[col];
#pragma unroll
            for (int r = 0; r < 4; r++) {
                const int rowg = m0 + wm * 64 + mi * 16 + g * 4 + r;
                const float v = acc[mi][ni][r] + bv;
                if (EPI == 0) {
                    const int which = col >> 8;
                    const int cc = col & 255;
                    const int h = cc >> 5, d = cc & 31;
                    const int bb = rowg >> 9, t = rowg & 511;
                    qkv[(size_t)which * NQTOT +
                        ((((size_t)bb * NH + h) * NT + t) * ND) + d] = f2bf(v);
                } else {
                    outf[(size_t)rowg * N + col] = v;
                }
            }
        }
    }
}

// ---------------- causal flash attention (whole-V-in-LDS, barrier-free loop) ----------------
// Grid 512: block = (half, bh); 4 waves x 64 q-rows (4 subs of 16). One V staging pass
// (swizzled transpose, up to 32 KB) + ONE barrier; then the causal k-loop runs with
// zero block barriers (per-wave P fencing only). K frags direct from global, reused
// by 4 subs. S^T = mfma(K,Q) swapped form: lane holds one q, softmax = in-lane tree + 2 shfls.
__global__ __launch_bounds__(256) void k_attn(const unsigned short* __restrict__ qkv,
                                              unsigned short* __restrict__ Ob) {
    __shared__ unsigned short Vt[32][512];    // [d][swizzled key col]
    __shared__ unsigned short Pl[4][16][72];  // per-wave P^T: [q][key]

    const int tid = threadIdx.x;
    const int lane = tid & 63;
    const int w = tid >> 6;
    const int i16 = lane & 15, g = lane >> 4;

    const int half = blockIdx.x >> 8;          // same-head halves 256 apart -> same XCD
    const int bh = blockIdx.x & 255;
    const unsigned short* Qp = qkv + (size_t)bh * NT * ND;
    const unsigned short* Kp = qkv + (size_t)NQTOT + (size_t)bh * NT * ND;
    const unsigned short* Vp = qkv + (size_t)2 * NQTOT + (size_t)bh * NT * ND;

    const int qbase = half * 256 + w * 64;
    const int ktmax = half * 4 + w;            // last (diagonal) 64-key tile for this wave
    const int npass = (half + 1) * 4;          // V staging passes (64 keys each)

    const int srow = tid >> 2;   // key within staging pass
    const int scr = tid & 3;     // d-chunk

    // stage V[0 .. npass*64) transposed + swizzled (same involution as r2/r3)
    for (int p = 0; p < npass; ++p) {
        short8 v = *reinterpret_cast<const short8*>(&Vp[(p * 64 + srow) * ND + scr * 8]);
#pragma unroll
        for (int j = 0; j < 8; j++) {
            const int swz = j ^ (scr << 1);    // (d&7)^(((d>>3)&3)<<1)
            Vt[scr * 8 + j][p * 64 + (srow & 7) + 8 * ((srow >> 3) ^ swz)] = (unsigned short)v[j];
        }
    }

    // Q fragments: 4 subs of 16 rows (B-side: row=q=lane&15, k contiguous g*8)
    short8 qf[4];
#pragma unroll
    for (int s = 0; s < 4; s++)
        qf[s] = *reinterpret_cast<const short8*>(&Qp[(qbase + s * 16 + i16) * ND + g * 8]);

    const f32x4 z4 = {0.f, 0.f, 0.f, 0.f};
    f32x4 O[4][2];                  // [sub][d-half]; O^T: d = dh*16+g*4+r, q col = i16
    float m_[4], l_[4];
#pragma unroll
    for (int s = 0; s < 4; s++) {
        O[s][0] = z4; O[s][1] = z4; m_[s] = -3e38f; l_[s] = 0.f;
    }

    __syncthreads();   // the only block barrier

    // scale with log2(e) folded: exp(x) = exp2(x*log2e)
    const float scale2 = 0.17677669529663687f * 1.4426950408889634f;

    for (int kt = 0; kt <= ktmax; ++kt) {
        // K fragments for this tile (coalesced 16B/lane, L2-resident), reused by 4 subs
        short8 kr[4];
#pragma unroll
        for (int kc = 0; kc < 4; kc++)
            kr[kc] = *reinterpret_cast<const short8*>(&Kp[(kt * 64 + kc * 16 + i16) * ND + g * 8]);
        // V fragments (A-side for PV: row=d, keys swizzled groups)
        short8 vf[2][2];
#pragma unroll
        for (int kc2 = 0; kc2 < 2; kc2++)
#pragma unroll
            for (int dh = 0; dh < 2; dh++) {
                const int dd = dh * 16 + i16;
                const int swzd = (dd & 7) ^ (((dd >> 3) & 3) << 1);
                vf[kc2][dh] = *reinterpret_cast<const short8*>(
                    &Vt[dd][kt * 64 + 8 * ((kc2 * 4 + g) ^ swzd)]);
            }

        const bool diag = (kt == ktmax);
#pragma unroll
        for (int sub = 0; sub < 4; ++sub) {
            // S^T = K Q^T: lane holds q = qbase+sub*16+i16, keys kc*16+g*4+r
            float s[4][4];
#pragma unroll
            for (int kc = 0; kc < 4; kc++) {
                if (!diag || kc <= sub) {
                    f32x4 sv = __builtin_amdgcn_mfma_f32_16x16x32_bf16(kr[kc], qf[sub], z4, 0, 0, 0);
                    if (diag && kc == sub) {
#pragma unroll
                        for (int r = 0; r < 4; r++)
                            s[kc][r] = (g * 4 + r <= i16) ? sv[r] * scale2 : -3e38f;
                    } else {
#pragma unroll
                        for (int r = 0; r < 4; r++) s[kc][r] = sv[r] * scale2;
                    }
                } else {
#pragma unroll
                    for (int r = 0; r < 4; r++) s[kc][r] = -3e38f;
                }
            }

            // online softmax: in-lane tree over 16 + 2 shfls across g-groups
            float tm = fmaxf(fmaxf(fmaxf(s[0][0], s[0][1]), fmaxf(s[0][2], s[0][3])),
                             fmaxf(fmaxf(s[1][0], s[1][1]), fmaxf(s[1][2], s[1][3])));
            tm = fmaxf(tm, fmaxf(fmaxf(fmaxf(s[2][0], s[2][1]), fmaxf(s[2][2], s[2][3])),
                                 fmaxf(fmaxf(s[3][0], s[3][1]), fmaxf(s[3][2], s[3][3]))));
            tm = fmaxf(tm, __shfl_xor(tm, 16, 64));
            tm = fmaxf(tm, __shfl_xor(tm, 32, 64));
            const float nm = fmaxf(m_[sub], tm);
            const float fr = exp2f(m_[sub] - nm);
            m_[sub] = nm;
            float ps = 0.f;
#pragma unroll
            for (int kc = 0; kc < 4; kc++)
#pragma unroll
                for (int r = 0; r < 4; r++) {
                    s[kc][r] = exp2f(s[kc][r] - nm);
                    ps += s[kc][r];
                }
            ps += __shfl_xor(ps, 16, 64);
            ps += __shfl_xor(ps, 32, 64);
            l_[sub] = l_[sub] * fr + ps;
            O[sub][0] *= fr; O[sub][1] *= fr;

            // P^T write: per kc, keys g*4..g*4+3 consecutive -> packed 8B store
#pragma unroll
            for (int kc = 0; kc < 4; kc++) {
                ushort4 pk;
                pk.x = f2bf(s[kc][0]); pk.y = f2bf(s[kc][1]);
                pk.z = f2bf(s[kc][2]); pk.w = f2bf(s[kc][3]);
                *reinterpret_cast<ushort4*>(&Pl[w][i16][kc * 16 + g * 4]) = pk;
            }
            // per-wave LDS fence (rule #18: fence + sched_barrier)
            asm volatile("s_waitcnt lgkmcnt(0)" ::: "memory");
            __builtin_amdgcn_sched_barrier(0);

            // O^T += V^T P^T  (A=vf rows=d, B=pf rows=q)
#pragma unroll
            for (int kc2 = 0; kc2 < 2; kc2++) {
                short8 pf = *reinterpret_cast<const short8*>(&Pl[w][i16][kc2 * 32 + g * 8]);
                O[sub][0] = __builtin_amdgcn_mfma_f32_16x16x32_bf16(vf[kc2][0], pf, O[sub][0], 0, 0, 0);
                O[sub][1] = __builtin_amdgcn_mfma_f32_16x16x32_bf16(vf[kc2][1], pf, O[sub][1], 0, 0, 0);
            }
        }
    }

    // epilogue: lane holds O^T for q=qbase+sub*16+i16, d=dh*16+g*4+r -> packed 8B stores
    const int b = bh >> 3, h = bh & 7;
#pragma unroll
    for (int sub = 0; sub < 4; ++sub) {
        const float inv = 1.f / l_[sub];
        const int q = qbase + sub * 16 + i16;
        const size_t base = ((size_t)(b * NT + q)) * NC + h * 32;
        ushort4 o0, o1;
        o0.x = f2bf(O[sub][0][0] * inv); o0.y = f2bf(O[sub][0][1] * inv);
        o0.z = f2bf(O[sub][0][2] * inv); o0.w = f2bf(O[sub][0][3] * inv);
        o1.x = f2bf(O[sub][1][0] * inv); o1.y = f2bf(O[sub][1][1] * inv);
        o1.z = f2bf(O[sub][1][2] * inv); o1.w = f2bf(O[sub][1][3] * inv);
        *reinterpret_cast<ushort4*>(&Ob[base + g * 4]) = o0;
        *reinterpret_cast<ushort4*>(&Ob[base + 16 + g * 4]) = o1;
    }
}

// ---------------- launch ----------------
extern "C" void kernel_launch(void* const* d_in, const int* in_sizes, int n_in,
                              void* d_out, int out_size, void* d_ws, size_t ws_size,
                              hipStream_t stream) {
    const float* x     = (const float*)d_in[0];
    const float* Wqkv  = (const float*)d_in[1];
    const float* bqkv  = (const float*)d_in[2];
    const float* Wproj = (const float*)d_in[3];
    const float* bproj = (const float*)d_in[4];
    float* out = (float*)d_out;

    unsigned short* WqkvT  = (unsigned short*)d_ws;                  // 768*256
    unsigned short* WprojT = WqkvT + (size_t)768 * 256;              // 256*256
    unsigned short* QKV    = WprojT + (size_t)256 * 256;             // 3 * NQTOT
    unsigned short* Ob     = QKV + (size_t)3 * NQTOT;                // 16384*256

    k_cvt_w2<<<256, 256, 0, stream>>>(Wqkv, WqkvT, Wproj, WprojT);

    k_gemm<0><<<128 * 6, 256, 0, stream>>>(x, WqkvT, bqkv, QKV, nullptr, 16384, 768, 256);
    k_attn<<<512, 256, 0, stream>>>(QKV, Ob);
    k_gemm<1><<<128 * 2, 256, 0, stream>>>(Ob, WprojT, bproj, nullptr, out, 16384, 256, 256);
}